// Round 1
// baseline (1198.418 us; speedup 1.0000x reference)
//
#include <hip/hip_runtime.h>

// ---------------- static problem configuration ----------------
#define E      32768
#define F      64
#define G      64
#define B      2
#define L      3
#define H      256
#define P      8              // B^L
#define D      4              // L+1
#define N0     (15*E)         // 491520 existing node rows
#define OFF3   (7*E)          // first row of level-3 nodes
#define NROWS  (P*E)          // 262144 parent rows to run the MLP on
#define BE     (B*E)          // 65536
#define EC0    1114112        // existing edge count (17 * BE)
#define ECN    (P*D*BE)       // 2097152 new edges
#define EC1    (EC0 + ECN)    // 3211264
#define NEV    (N0 + P*BE)    // 1015808 events (also = total node rows)

// Output layout (all float32, concatenated in return order):
//   x_new       : NEV * F elements                      at 0
//   edge_index  : 2 * EC1 (row 0 = src, row 1 = tgt)    at OXE
//   edge_attr   : EC1                                   at OEA
//   event_new   : NEV                                   at OEV
#define SXN   (NEV * F)          // 65011712
#define OXE   SXN
#define OEA   (OXE + 2*EC1)      // 71434240
#define OEV   (OEA + EC1)        // 74645504

#define TM 32   // MLP rows per block

// ---------------- kernel 1: copy x rows ----------------
__global__ __launch_bounds__(256) void copyx_kernel(const float4* __restrict__ x,
                                                    float4* __restrict__ out) {
    int i = blockIdx.x * 256 + threadIdx.x;
    if (i < (N0 * F) / 4) out[i] = x[i];
}

// ---------------- kernel 2: edges / attrs / events ----------------
__global__ __launch_bounds__(256) void aux_kernel(const int* __restrict__ ei,
                                                  const int* __restrict__ ea,
                                                  const int* __restrict__ ev,
                                                  float* __restrict__ out) {
    int i = blockIdx.x * 256 + threadIdx.x;
    if (i < EC1) {
        int src, tgt, attr;
        if (i < EC0) {
            src  = ei[i];
            tgt  = ei[EC0 + i];
            attr = ea[i];
        } else {
            int k = i - EC0;
            int p = k >> 18;            // D*BE = 262144 = 2^18
            int r = k & (262144 - 1);
            int d = r >> 16;            // BE = 65536 = 2^16
            int j = r & (BE - 1);
            // ancestor offset for degree d+1: E*((8>>d)-1)
            src  = E * (((8 >> d) - 1) + (p >> d)) + (j & (E - 1));
            tgt  = N0 + p * BE + j;
            attr = d + 1;
        }
        out[OXE + i]       = (float)src;
        out[OXE + EC1 + i] = (float)tgt;
        out[OEA + i]       = (float)attr;
    }
    if (i < NEV) {
        int v = (i < N0) ? ev[i] : ((i - N0) & (E - 1));
        out[OEV + i] = (float)v;
    }
}

// ---------------- kernel 3: per-row MLP (fp32 vector) ----------------
// rows indexed by row = p*E + e ; input x row = OFF3 + row ; output floats at
// N0*F + row*128 + c  (c = b*64 + f), which is exactly proj.reshape(P*E*B, F).
__global__ __launch_bounds__(256) void mlp_kernel(const float* __restrict__ x,
                                                  const int* __restrict__ ev,
                                                  const float* __restrict__ gf,
                                                  const float* __restrict__ W1,
                                                  const float* __restrict__ b1,
                                                  const float* __restrict__ W2,
                                                  const float* __restrict__ b2,
                                                  float* __restrict__ out) {
    __shared__ float hsh[TM * 128];   // input features tile
    __shared__ float hid[TM * 256];   // hidden activations tile
    const int tid  = threadIdx.x;
    const int row0 = blockIdx.x * TM;

    // phase 1: stage h = [x_row | gf[event[x_row]]] for TM rows
    const float4* x4 = (const float4*)x;
    const float4* g4 = (const float4*)gf;
    #pragma unroll
    for (int k = 0; k < 4; ++k) {
        int q = tid + 256 * k;        // 0..1023
        int r = q >> 5;               // tile row
        int c = q & 31;               // float4 column 0..31
        int grow = OFF3 + row0 + r;
        float4 v;
        if (c < 16) v = x4[grow * 16 + c];
        else        v = g4[ev[grow] * 16 + (c - 16)];
        *(float4*)&hsh[r * 128 + c * 4] = v;
    }
    __syncthreads();

    // phase 2: hidden[r][tid] = relu(h[r] . W1[:,tid] + b1[tid])
    float acc[TM];
    #pragma unroll
    for (int r = 0; r < TM; ++r) acc[r] = 0.f;
    for (int k = 0; k < 128; k += 4) {
        float w0 = W1[(k + 0) * 256 + tid];
        float w1 = W1[(k + 1) * 256 + tid];
        float w2 = W1[(k + 2) * 256 + tid];
        float w3 = W1[(k + 3) * 256 + tid];
        #pragma unroll
        for (int r = 0; r < TM; ++r) {
            float4 hv = *(const float4*)&hsh[r * 128 + k];
            acc[r] += hv.x * w0 + hv.y * w1 + hv.z * w2 + hv.w * w3;
        }
    }
    {
        float bb = b1[tid];
        #pragma unroll
        for (int r = 0; r < TM; ++r)
            hid[r * 256 + tid] = fmaxf(acc[r] + bb, 0.f);
    }
    __syncthreads();

    // phase 3: out[r][col] = hidden[r] . W2[:,col] + b2[col]
    const int col   = tid & 127;
    const int rbase = (tid >> 7) * (TM / 2);
    float acc2[TM / 2];
    #pragma unroll
    for (int r = 0; r < TM / 2; ++r) acc2[r] = 0.f;
    for (int k = 0; k < 256; k += 4) {
        float w0 = W2[(k + 0) * 128 + col];
        float w1 = W2[(k + 1) * 128 + col];
        float w2 = W2[(k + 2) * 128 + col];
        float w3 = W2[(k + 3) * 128 + col];
        #pragma unroll
        for (int r = 0; r < TM / 2; ++r) {
            float4 hv = *(const float4*)&hid[(rbase + r) * 256 + k];
            acc2[r] += hv.x * w0 + hv.y * w1 + hv.z * w2 + hv.w * w3;
        }
    }
    {
        float bb = b2[col];
        #pragma unroll
        for (int r = 0; r < TM / 2; ++r)
            out[N0 * F + (row0 + rbase + r) * 128 + col] = acc2[r] + bb;
    }
}

// ---------------- launcher ----------------
extern "C" void kernel_launch(void* const* d_in, const int* in_sizes, int n_in,
                              void* d_out, int out_size, void* d_ws, size_t ws_size,
                              hipStream_t stream) {
    const float* x  = (const float*)d_in[0];
    const int*   ei = (const int*)d_in[1];
    const int*   ea = (const int*)d_in[2];
    const int*   ev = (const int*)d_in[3];
    const float* gf = (const float*)d_in[4];
    const float* W1 = (const float*)d_in[5];
    const float* b1 = (const float*)d_in[6];
    const float* W2 = (const float*)d_in[7];
    const float* b2 = (const float*)d_in[8];
    float* out = (float*)d_out;

    // MLP on the 262144 level-3 parent rows
    mlp_kernel<<<NROWS / TM, 256, 0, stream>>>(x, ev, gf, W1, b1, W2, b2, out);
    // copy existing x rows
    copyx_kernel<<<((N0 * F) / 4 + 255) / 256, 256, 0, stream>>>((const float4*)x,
                                                                 (float4*)out);
    // edges + attrs + events
    aux_kernel<<<(EC1 + 255) / 256, 256, 0, stream>>>(ei, ea, ev, out);
}

// Round 2
// 463.072 us; speedup vs baseline: 2.5880x; 2.5880x over previous
//
#include <hip/hip_runtime.h>

// ---------------- static problem configuration ----------------
#define E      32768
#define F      64
#define G      64
#define B      2
#define L      3
#define H      256
#define P      8              // B^L
#define D      4              // L+1
#define N0     (15*E)         // 491520 existing node rows
#define OFF3   (7*E)          // first row of level-3 nodes
#define NROWS  (P*E)          // 262144 parent rows to run the MLP on
#define BE     (B*E)          // 65536
#define EC0    1114112        // existing edge count
#define ECN    (P*D*BE)       // 2097152 new edges
#define EC1    (EC0 + ECN)    // 3211264
#define NEV    (N0 + P*BE)    // 1015808

// Output layout (all float32, concatenated):
#define SXN   (NEV * F)          // 65011712
#define OXE   SXN
#define OEA   (OXE + 2*EC1)      // 71434240
#define OEV   (OEA + EC1)        // 74645504

using short8  = __attribute__((ext_vector_type(8))) short;
using floatx4 = __attribute__((ext_vector_type(4))) float;

__device__ __forceinline__ ushort f2b(float f) {
    unsigned u = __float_as_uint(f);
    return (ushort)((u + 0x7fffu + ((u >> 16) & 1u)) >> 16);
}

// ---------------- kernel 0: pack W1/W2 into bf16 MFMA B-fragment order ------
// W1pack[t*8+j], t = ((w*4+kt)*4+nt)*64+lane : W1[kt*32+quad*8+j][w*64+nt*16+l16]
// W2pack at +32768, t2 = ((w*8+kt)*2+nt)*64+lane : W2[kt*32+quad*8+j][w*32+nt*16+l16]
__global__ __launch_bounds__(256) void pack_kernel(const float* __restrict__ W1,
                                                   const float* __restrict__ W2,
                                                   ushort* __restrict__ wp) {
    int t = blockIdx.x * 256 + threadIdx.x;   // 0..8191
    ushort tmp[8];
    if (t < 4096) {
        int lane = t & 63, nt = (t >> 6) & 3, kt = (t >> 8) & 3, w = (t >> 10) & 3;
        int col = w * 64 + nt * 16 + (lane & 15);
        int kb  = kt * 32 + (lane >> 4) * 8;
        #pragma unroll
        for (int j = 0; j < 8; ++j) tmp[j] = f2b(W1[(kb + j) * 256 + col]);
        uint4 v = make_uint4((unsigned)tmp[0] | ((unsigned)tmp[1] << 16),
                             (unsigned)tmp[2] | ((unsigned)tmp[3] << 16),
                             (unsigned)tmp[4] | ((unsigned)tmp[5] << 16),
                             (unsigned)tmp[6] | ((unsigned)tmp[7] << 16));
        *(uint4*)(wp + t * 8) = v;
    } else {
        int t2 = t - 4096;
        int lane = t2 & 63, nt = (t2 >> 6) & 1, kt = (t2 >> 7) & 7, w = (t2 >> 10) & 3;
        int col = w * 32 + nt * 16 + (lane & 15);
        int kb  = kt * 32 + (lane >> 4) * 8;
        #pragma unroll
        for (int j = 0; j < 8; ++j) tmp[j] = f2b(W2[(kb + j) * 128 + col]);
        uint4 v = make_uint4((unsigned)tmp[0] | ((unsigned)tmp[1] << 16),
                             (unsigned)tmp[2] | ((unsigned)tmp[3] << 16),
                             (unsigned)tmp[4] | ((unsigned)tmp[5] << 16),
                             (unsigned)tmp[6] | ((unsigned)tmp[7] << 16));
        *(uint4*)(wp + 32768 + t2 * 8) = v;
    }
}

// ---------------- kernel 1: copy x rows ----------------
__global__ __launch_bounds__(256) void copyx_kernel(const float4* __restrict__ x,
                                                    float4* __restrict__ out) {
    int i = blockIdx.x * 256 + threadIdx.x;
    if (i < (N0 * F) / 4) out[i] = x[i];
}

// ---------------- kernel 2: edges / attrs / events (4-wide) ----------------
__global__ __launch_bounds__(256) void aux_kernel(const int* __restrict__ ei,
                                                  const int* __restrict__ ea,
                                                  const int* __restrict__ ev,
                                                  float* __restrict__ out) {
    int i4 = blockIdx.x * 256 + threadIdx.x;
    if (i4 < EC1 / 4) {
        int i = i4 * 4;
        float4 sf, tf, af;
        if (i < EC0) {
            int4 sv = ((const int4*)ei)[i4];
            int4 tv = ((const int4*)(ei + EC0))[i4];
            int4 av = ((const int4*)ea)[i4];
            sf = make_float4((float)sv.x, (float)sv.y, (float)sv.z, (float)sv.w);
            tf = make_float4((float)tv.x, (float)tv.y, (float)tv.z, (float)tv.w);
            af = make_float4((float)av.x, (float)av.y, (float)av.z, (float)av.w);
        } else {
            float s[4], t[4], a[4];
            #pragma unroll
            for (int q = 0; q < 4; ++q) {
                int k = i + q - EC0;
                int p = k >> 18;
                int r = k & (262144 - 1);
                int d = r >> 16;
                int j = r & (BE - 1);
                s[q] = (float)(E * (((8 >> d) - 1) + (p >> d)) + (j & (E - 1)));
                t[q] = (float)(N0 + p * BE + j);
                a[q] = (float)(d + 1);
            }
            sf = make_float4(s[0], s[1], s[2], s[3]);
            tf = make_float4(t[0], t[1], t[2], t[3]);
            af = make_float4(a[0], a[1], a[2], a[3]);
        }
        ((float4*)(out + OXE))[i4]       = sf;
        ((float4*)(out + OXE + EC1))[i4] = tf;
        ((float4*)(out + OEA))[i4]       = af;
    }
    if (i4 < NEV / 4) {
        int i = i4 * 4;
        float4 v;
        if (i < N0) {
            int4 e = ((const int4*)ev)[i4];
            v = make_float4((float)e.x, (float)e.y, (float)e.z, (float)e.w);
        } else {
            int base = (i - N0) & (E - 1);
            v = make_float4((float)base, (float)(base + 1), (float)(base + 2), (float)(base + 3));
        }
        ((float4*)(out + OEV))[i4] = v;
    }
}

// ---------------- kernel 3: fused MLP via bf16 MFMA ----------------
// 64 rows/block, 4 waves. Wave w: GEMM1 cols [w*64,w*64+64), GEMM2 cols [w*32,w*32+32).
#define HP1 136   // h tile row pitch (128 + 8 pad), bf16 elems; 272 B, 16B-aligned
#define HP2 264   // hidden tile row pitch (256 + 8), 528 B, 16B-aligned
__global__ __launch_bounds__(256, 2) void mlp_mfma(const float* __restrict__ x,
                                                   const float* __restrict__ gf,
                                                   const ushort* __restrict__ wpack,
                                                   const float* __restrict__ b1,
                                                   const float* __restrict__ b2,
                                                   float* __restrict__ out) {
    __shared__ ushort hsh[64 * HP1];
    __shared__ ushort hid[64 * HP2];
    const int tid  = threadIdx.x;
    const int wave = tid >> 6, lane = tid & 63;
    const int quad = lane >> 4, l16 = lane & 15;
    const int row0 = blockIdx.x * 64;

    // ---- preload weight fragments (constant per block) ----
    short8 w1f[4][4];   // [kt][nt]  K=128, N-slice 64
    {
        const ushort* wp1 = wpack + wave * 8192;
        #pragma unroll
        for (int kt = 0; kt < 4; ++kt)
            #pragma unroll
            for (int nt = 0; nt < 4; ++nt)
                w1f[kt][nt] = *(const short8*)(wp1 + (kt * 4 + nt) * 512 + lane * 8);
    }
    short8 w2f[8][2];   // [kt][nt]  K=256, N-slice 32
    {
        const ushort* wp2 = wpack + 32768 + wave * 8192;
        #pragma unroll
        for (int kt = 0; kt < 8; ++kt)
            #pragma unroll
            for (int nt = 0; nt < 2; ++nt)
                w2f[kt][nt] = *(const short8*)(wp2 + (kt * 2 + nt) * 512 + lane * 8);
    }

    // ---- stage h = [x_row | gf[e]] as bf16: 64 rows x 128 ----
    // event for level-3 row (row0+r) is (row0+r) & (E-1) analytically.
    #pragma unroll
    for (int it = 0; it < 4; ++it) {
        int q  = tid + 256 * it;      // 0..1023
        int r  = q >> 4;              // row 0..63
        int cc = q & 15;              // 8-elem chunk 0..15
        int rg = row0 + r;
        const float* src = (cc < 8) ? (x + (OFF3 + rg) * 64 + cc * 8)
                                    : (gf + (rg & (E - 1)) * 64 + (cc - 8) * 8);
        float4 a  = *(const float4*)src;
        float4 bv = *(const float4*)(src + 4);
        uint4 v = make_uint4((unsigned)f2b(a.x)  | ((unsigned)f2b(a.y)  << 16),
                             (unsigned)f2b(a.z)  | ((unsigned)f2b(a.w)  << 16),
                             (unsigned)f2b(bv.x) | ((unsigned)f2b(bv.y) << 16),
                             (unsigned)f2b(bv.z) | ((unsigned)f2b(bv.w) << 16));
        *(uint4*)&hsh[r * HP1 + cc * 8] = v;
    }
    __syncthreads();

    // ---- GEMM1: hidden[64 x 256] = relu(h @ W1 + b1), wave does N-slice 64 ----
    {
        floatx4 acc[4][4];
        #pragma unroll
        for (int mt = 0; mt < 4; ++mt)
            #pragma unroll
            for (int nt = 0; nt < 4; ++nt)
                acc[mt][nt] = (floatx4){0.f, 0.f, 0.f, 0.f};
        #pragma unroll
        for (int mt = 0; mt < 4; ++mt) {
            short8 af[4];
            #pragma unroll
            for (int kt = 0; kt < 4; ++kt)
                af[kt] = *(const short8*)&hsh[(mt * 16 + l16) * HP1 + kt * 32 + quad * 8];
            #pragma unroll
            for (int nt = 0; nt < 4; ++nt)
                #pragma unroll
                for (int kt = 0; kt < 4; ++kt)
                    acc[mt][nt] = __builtin_amdgcn_mfma_f32_16x16x32_bf16(
                        af[kt], w1f[kt][nt], acc[mt][nt], 0, 0, 0);
        }
        // epilogue: bias + relu -> bf16 -> hid LDS
        #pragma unroll
        for (int nt = 0; nt < 4; ++nt) {
            int col = wave * 64 + nt * 16 + l16;
            float bb = b1[col];
            #pragma unroll
            for (int mt = 0; mt < 4; ++mt) {
                #pragma unroll
                for (int i = 0; i < 4; ++i) {
                    int m = mt * 16 + quad * 4 + i;
                    hid[m * HP2 + col] = f2b(fmaxf(acc[mt][nt][i] + bb, 0.f));
                }
            }
        }
    }
    __syncthreads();

    // ---- GEMM2: out[64 x 128] = hidden @ W2 + b2, wave does N-slice 32 ----
    {
        floatx4 acc[4][2];
        #pragma unroll
        for (int mt = 0; mt < 4; ++mt)
            #pragma unroll
            for (int nt = 0; nt < 2; ++nt)
                acc[mt][nt] = (floatx4){0.f, 0.f, 0.f, 0.f};
        #pragma unroll
        for (int mt = 0; mt < 4; ++mt) {
            short8 hf[8];
            #pragma unroll
            for (int kt = 0; kt < 8; ++kt)
                hf[kt] = *(const short8*)&hid[(mt * 16 + l16) * HP2 + kt * 32 + quad * 8];
            #pragma unroll
            for (int nt = 0; nt < 2; ++nt)
                #pragma unroll
                for (int kt = 0; kt < 8; ++kt)
                    acc[mt][nt] = __builtin_amdgcn_mfma_f32_16x16x32_bf16(
                        hf[kt], w2f[kt][nt], acc[mt][nt], 0, 0, 0);
        }
        #pragma unroll
        for (int nt = 0; nt < 2; ++nt) {
            int col = wave * 32 + nt * 16 + l16;
            float bb = b2[col];
            #pragma unroll
            for (int mt = 0; mt < 4; ++mt) {
                #pragma unroll
                for (int i = 0; i < 4; ++i) {
                    int m = mt * 16 + quad * 4 + i;
                    out[N0 * F + (row0 + m) * 128 + col] = acc[mt][nt][i] + bb;
                }
            }
        }
    }
}

// ---------------- launcher ----------------
extern "C" void kernel_launch(void* const* d_in, const int* in_sizes, int n_in,
                              void* d_out, int out_size, void* d_ws, size_t ws_size,
                              hipStream_t stream) {
    const float* x  = (const float*)d_in[0];
    const int*   ei = (const int*)d_in[1];
    const int*   ea = (const int*)d_in[2];
    const int*   ev = (const int*)d_in[3];
    const float* gf = (const float*)d_in[4];
    const float* W1 = (const float*)d_in[5];
    const float* W2 = (const float*)d_in[7];
    const float* b1 = (const float*)d_in[6];
    const float* b2 = (const float*)d_in[8];
    float* out = (float*)d_out;
    ushort* wpack = (ushort*)d_ws;   // 65536 bf16 = 128 KB

    pack_kernel<<<32, 256, 0, stream>>>(W1, W2, wpack);
    mlp_mfma<<<NROWS / 64, 256, 0, stream>>>(x, gf, wpack, b1, b2, out);
    copyx_kernel<<<((N0 * F) / 4 + 255) / 256, 256, 0, stream>>>((const float4*)x,
                                                                 (float4*)out);
    aux_kernel<<<(EC1 / 4 + 255) / 256, 256, 0, stream>>>(ei, ea, ev, out);
}